// Round 8
// baseline (174.490 us; speedup 1.0000x reference)
//
#include <hip/hip_runtime.h>

#define NGRAPHS 2048
#define DIN     1536
#define DH1     64
#define DH2     32
#define BLOCKS  768     // 3 blocks/CU: 18 waves/CU, 2.67 steal-units/block

typedef float fvec4 __attribute__((ext_vector_type(4)));

// ---------------- Pass 1: segment offsets (batch sorted) + zero counter -----
__global__ void find_offsets_kernel(const int* __restrict__ batch, int n,
                                    int* __restrict__ offsets,
                                    int* __restrict__ counter) {
    int i = blockIdx.x * blockDim.x + threadIdx.x;
    if (i == 0) *counter = 0;
    if (i >= n) return;
    int b = batch[i];
    int prev = (i == 0) ? -1 : batch[i - 1];
    for (int g = prev + 1; g <= b; ++g) offsets[g] = i;
    if (i == n - 1) {
        for (int g = b + 1; g <= NGRAPHS; ++g) offsets[g] = n;
    }
}

// ---------------- Pass 2: persistent, work-stealing, software-pipelined -----
// Per block, two graphs in flight: phase A streams graph g_nxt (rows ->
// register accumulators, 6 outstanding loads/lane) INTERLEAVED with layer-1
// of g_cur (mean in LDS[cb], W1 L2-hot); phase B runs cheap L2/L3 of g_cur.
// Double-buffered mean_s. Deterministic: one block computes a whole graph
// with a fixed summation order independent of assignment.
__global__ __launch_bounds__(384) void pool_mlp_pipe_kernel(
    const float* __restrict__ features,
    const int* __restrict__ offsets,
    const float* __restrict__ W1, const float* __restrict__ b1,
    const float* __restrict__ W2, const float* __restrict__ b2,
    const float* __restrict__ W3, const float* __restrict__ b3,
    float* __restrict__ out,
    int* __restrict__ counter)
{
    const int tid  = threadIdx.x;
    const int lane = tid & 63;
    const int wave = tid >> 6;

    __shared__ float mean_s[2][DIN];
    __shared__ float h1_s[DH1];
    __shared__ float h2_s[DH2];
    __shared__ int   next_s;

    const fvec4* __restrict__ F4 = reinterpret_cast<const fvec4*>(features);

    // prologue: grab first unit
    if (tid == 0) next_s = atomicAdd(counter, 1);
    __syncthreads();
    int g_nxt = next_s;        // graph being streamed this iteration
    int g_cur = NGRAPHS;       // graph whose MLP runs this iteration (invalid)
    int cb = 0;                // mean_s[cb] belongs to g_cur

    while (g_cur < NGRAPHS || g_nxt < NGRAPHS) {
        // ================= phase A =================
        if (tid == 0) {
            int f = (g_nxt < NGRAPHS) ? atomicAdd(counter, 1) : NGRAPHS;
            next_s = f;
        }
        const int nb = cb ^ 1;

        int s2 = 0, e2 = 0;
        if (g_nxt < NGRAPHS) { s2 = offsets[g_nxt]; e2 = offsets[g_nxt + 1]; }
        int r = s2;                                  // wave-uniform row cursor
        fvec4 acc0 = (fvec4)(0.f), acc1 = (fvec4)(0.f);

        if (g_cur < NGRAPHS) {
            // fused: layer-1 of g_cur + stream of g_nxt (6 rows per output)
            const fvec4* __restrict__ m4 =
                reinterpret_cast<const fvec4*>(mean_s[cb]);
            for (int jj = 0; jj < 11; ++jj) {
                const int j = wave + 6 * jj;         // waves 4,5 hit j>=64 at jj=10
                fvec4 v0 = (fvec4)(0.f), v1 = (fvec4)(0.f), v2 = (fvec4)(0.f);
                fvec4 v3 = (fvec4)(0.f), v4 = (fvec4)(0.f), v5 = (fvec4)(0.f);
                if (r + 0 < e2) v0 = __builtin_nontemporal_load(&F4[(size_t)(r + 0) * (DIN / 4) + tid]);
                if (r + 1 < e2) v1 = __builtin_nontemporal_load(&F4[(size_t)(r + 1) * (DIN / 4) + tid]);
                if (r + 2 < e2) v2 = __builtin_nontemporal_load(&F4[(size_t)(r + 2) * (DIN / 4) + tid]);
                if (r + 3 < e2) v3 = __builtin_nontemporal_load(&F4[(size_t)(r + 3) * (DIN / 4) + tid]);
                if (r + 4 < e2) v4 = __builtin_nontemporal_load(&F4[(size_t)(r + 4) * (DIN / 4) + tid]);
                if (r + 5 < e2) v5 = __builtin_nontemporal_load(&F4[(size_t)(r + 5) * (DIN / 4) + tid]);
                int ladv = e2 - r; ladv = (ladv < 0) ? 0 : (ladv > 6 ? 6 : ladv);
                r += ladv;

                if (j < DH1) {
                    const fvec4* __restrict__ w4 =
                        reinterpret_cast<const fvec4*>(W1 + (size_t)j * DIN);
                    float d = 0.f;
                    #pragma unroll
                    for (int k = 0; k < 6; ++k) {
                        fvec4 w = w4[k * 64 + lane];
                        fvec4 m = m4[k * 64 + lane];
                        d += m.x * w.x + m.y * w.y + m.z * w.z + m.w * w.w;
                    }
                    #pragma unroll
                    for (int off = 32; off; off >>= 1) d += __shfl_xor(d, off, 64);
                    if (lane == 0) h1_s[j] = fmaxf(d + b1[j], 0.f);
                }
                acc0 += v0 + v2 + v4;
                acc1 += v1 + v3 + v5;
            }
        }
        // drain remaining rows of g_nxt (also the whole stream on prologue)
        for (; r + 4 <= e2; r += 4) {
            fvec4 u0 = __builtin_nontemporal_load(&F4[(size_t)(r + 0) * (DIN / 4) + tid]);
            fvec4 u1 = __builtin_nontemporal_load(&F4[(size_t)(r + 1) * (DIN / 4) + tid]);
            fvec4 u2 = __builtin_nontemporal_load(&F4[(size_t)(r + 2) * (DIN / 4) + tid]);
            fvec4 u3 = __builtin_nontemporal_load(&F4[(size_t)(r + 3) * (DIN / 4) + tid]);
            acc0 += u0 + u2;
            acc1 += u1 + u3;
        }
        for (; r < e2; ++r)
            acc0 += __builtin_nontemporal_load(&F4[(size_t)r * (DIN / 4) + tid]);

        if (g_nxt < NGRAPHS) {
            const int cnt = e2 - s2;
            const float inv = 1.0f / (float)(cnt > 1 ? cnt : 1);
            fvec4 mm = (acc0 + acc1) * inv;
            reinterpret_cast<fvec4*>(mean_s[nb])[tid] = mm;
        }
        __syncthreads();            // publishes h1_s, mean_s[nb], next_s
        const int g_fut = next_s;   // every thread snapshots the grab

        // ================= phase B =================
        if (g_cur < NGRAPHS) {
            for (int j = wave; j < DH2; j += 6) {
                float a = h1_s[lane] * W2[(size_t)j * DH1 + lane];
                #pragma unroll
                for (int off = 32; off; off >>= 1) a += __shfl_xor(a, off, 64);
                if (lane == 0) h2_s[j] = fmaxf(a + b2[j], 0.f);
            }
        }
        __syncthreads();            // publishes h2_s; orders g_fut reads
        if (g_cur < NGRAPHS && wave == 0) {
            float a = (lane < DH2) ? h2_s[lane] * W3[lane] : 0.f;
            #pragma unroll
            for (int off = 32; off; off >>= 1) a += __shfl_xor(a, off, 64);
            if (lane == 0) out[g_cur] = a + b3[0];
        }

        // rotate pipeline
        g_cur = g_nxt;
        g_nxt = g_fut;
        cb = nb;
    }
}

extern "C" void kernel_launch(void* const* d_in, const int* in_sizes, int n_in,
                              void* d_out, int out_size, void* d_ws, size_t ws_size,
                              hipStream_t stream) {
    const float* features = (const float*)d_in[0];
    const int*   batch    = (const int*)d_in[1];   // int64 in ref -> int32 (x64 off)
    const float* W1 = (const float*)d_in[2];
    const float* b1 = (const float*)d_in[3];
    const float* W2 = (const float*)d_in[4];
    const float* b2 = (const float*)d_in[5];
    const float* W3 = (const float*)d_in[6];
    const float* b3 = (const float*)d_in[7];
    float* out = (float*)d_out;

    const int n = in_sizes[1];                 // 131072 rows
    int* counter = (int*)d_ws;                 // [0]: work-queue counter
    int* offsets = (int*)d_ws + 64;            // (NGRAPHS+1) ints, 256B-aligned

    find_offsets_kernel<<<(n + 255) / 256, 256, 0, stream>>>(batch, n, offsets,
                                                             counter);
    pool_mlp_pipe_kernel<<<BLOCKS, 384, 0, stream>>>(features, offsets,
                                                     W1, b1, W2, b2, W3, b3,
                                                     out, counter);
}

// Round 9
// 164.882 us; speedup vs baseline: 1.0583x; 1.0583x over previous
//
#include <hip/hip_runtime.h>

#define NGRAPHS 2048
#define DIN     1536
#define DH1     64
#define DH2     32
#define POOL_BLOCKS 1280   // 5 blocks/CU x 256 CU — all co-resident, work-stealing

typedef float fvec4 __attribute__((ext_vector_type(4)));

// ---------------- Pass 1: segment offsets (batch sorted) + zero counter -----
__global__ void find_offsets_kernel(const int* __restrict__ batch, int n,
                                    int* __restrict__ offsets,
                                    int* __restrict__ counter) {
    int i = blockIdx.x * blockDim.x + threadIdx.x;
    if (i == 0) *counter = 0;                      // reset work queue every call
    if (i >= n) return;
    int b = batch[i];
    int prev = (i == 0) ? -1 : batch[i - 1];
    for (int g = prev + 1; g <= b; ++g) offsets[g] = i;
    if (i == n - 1) {
        for (int g = b + 1; g <= NGRAPHS; ++g) offsets[g] = n;
    }
}

// ---------------- Pass 2: persistent fused pool+MLP with work-stealing ------
// 1280 blocks x 384 threads (6 waves). Work-stealing equalizes finish times.
// Row loop unrolled x8 (mean graph = 64 rows = 8 iters): 8 independent
// global_load_dwordx4 chains per lane = 8KB/wave in flight.
__global__ __launch_bounds__(384) void pool_mlp_ws_kernel(
    const float* __restrict__ features,
    const int* __restrict__ offsets,
    const float* __restrict__ W1, const float* __restrict__ b1,
    const float* __restrict__ W2, const float* __restrict__ b2,
    const float* __restrict__ W3, const float* __restrict__ b3,
    float* __restrict__ out,
    int* __restrict__ counter)
{
    const int tid  = threadIdx.x;
    const int lane = tid & 63;
    const int wave = tid >> 6;

    __shared__ float mean_s[DIN];
    __shared__ float h1_s[DH1];
    __shared__ float h2_s[DH2];
    __shared__ int   g_s;

    const fvec4* __restrict__ F4 = reinterpret_cast<const fvec4*>(features);

    for (;;) {
        if (tid == 0) g_s = atomicAdd(counter, 1);
        __syncthreads();
        const int g = g_s;
        if (g >= NGRAPHS) break;

        const int s = offsets[g];
        const int e = offsets[g + 1];

        // ---- segment sum: coalesced stream, x8 row unroll, nontemporal ----
        fvec4 a0 = (fvec4)(0.f), a1 = (fvec4)(0.f), a2 = (fvec4)(0.f), a3 = (fvec4)(0.f);
        fvec4 a4 = (fvec4)(0.f), a5 = (fvec4)(0.f), a6 = (fvec4)(0.f), a7 = (fvec4)(0.f);
        int r = s;
        for (; r + 8 <= e; r += 8) {
            fvec4 v0 = __builtin_nontemporal_load(&F4[(size_t)(r + 0) * (DIN / 4) + tid]);
            fvec4 v1 = __builtin_nontemporal_load(&F4[(size_t)(r + 1) * (DIN / 4) + tid]);
            fvec4 v2 = __builtin_nontemporal_load(&F4[(size_t)(r + 2) * (DIN / 4) + tid]);
            fvec4 v3 = __builtin_nontemporal_load(&F4[(size_t)(r + 3) * (DIN / 4) + tid]);
            fvec4 v4 = __builtin_nontemporal_load(&F4[(size_t)(r + 4) * (DIN / 4) + tid]);
            fvec4 v5 = __builtin_nontemporal_load(&F4[(size_t)(r + 5) * (DIN / 4) + tid]);
            fvec4 v6 = __builtin_nontemporal_load(&F4[(size_t)(r + 6) * (DIN / 4) + tid]);
            fvec4 v7 = __builtin_nontemporal_load(&F4[(size_t)(r + 7) * (DIN / 4) + tid]);
            a0 += v0; a1 += v1; a2 += v2; a3 += v3;
            a4 += v4; a5 += v5; a6 += v6; a7 += v7;
        }
        for (; r + 2 <= e; r += 2) {
            fvec4 v0 = __builtin_nontemporal_load(&F4[(size_t)(r + 0) * (DIN / 4) + tid]);
            fvec4 v1 = __builtin_nontemporal_load(&F4[(size_t)(r + 1) * (DIN / 4) + tid]);
            a0 += v0; a1 += v1;
        }
        for (; r < e; ++r)
            a0 += __builtin_nontemporal_load(&F4[(size_t)r * (DIN / 4) + tid]);

        a0 += a4; a1 += a5; a2 += a6; a3 += a7;
        a0 += a2; a1 += a3;
        a0 += a1;

        const int cnt = e - s;
        const float inv = 1.0f / (float)(cnt > 1 ? cnt : 1);
        a0 *= inv;
        reinterpret_cast<fvec4*>(mean_s)[tid] = a0;
        __syncthreads();

        // ---- layer 1: wave-cooperative, coalesced W1 (hot in L2) ----
        const fvec4* __restrict__ m4 = reinterpret_cast<const fvec4*>(mean_s);
        for (int j = wave; j < DH1; j += 6) {
            const fvec4* __restrict__ w4 =
                reinterpret_cast<const fvec4*>(W1 + (size_t)j * DIN);
            float acc = 0.f;
            #pragma unroll
            for (int k = 0; k < DIN / 4 / 64; ++k) {      // 6 iters
                fvec4 w = w4[k * 64 + lane];
                fvec4 m = m4[k * 64 + lane];
                acc += m.x * w.x + m.y * w.y + m.z * w.z + m.w * w.w;
            }
            #pragma unroll
            for (int off = 32; off; off >>= 1) acc += __shfl_xor(acc, off, 64);
            if (lane == 0) h1_s[j] = fmaxf(acc + b1[j], 0.f);
        }
        __syncthreads();

        // ---- layer 2 ----
        for (int j = wave; j < DH2; j += 6) {
            float acc = h1_s[lane] * W2[(size_t)j * DH1 + lane];
            #pragma unroll
            for (int off = 32; off; off >>= 1) acc += __shfl_xor(acc, off, 64);
            if (lane == 0) h2_s[j] = fmaxf(acc + b2[j], 0.f);
        }
        __syncthreads();

        // ---- layer 3 ----
        if (wave == 0) {
            float acc = (lane < DH2) ? h2_s[lane] * W3[lane] : 0.f;
            #pragma unroll
            for (int off = 32; off; off >>= 1) acc += __shfl_xor(acc, off, 64);
            if (lane == 0) out[g] = acc + b3[0];
        }
        __syncthreads();   // protect g_s / mean_s / h*_s before next grab
    }
}

extern "C" void kernel_launch(void* const* d_in, const int* in_sizes, int n_in,
                              void* d_out, int out_size, void* d_ws, size_t ws_size,
                              hipStream_t stream) {
    const float* features = (const float*)d_in[0];
    const int*   batch    = (const int*)d_in[1];   // int64 in ref -> int32 (x64 off)
    const float* W1 = (const float*)d_in[2];
    const float* b1 = (const float*)d_in[3];
    const float* W2 = (const float*)d_in[4];
    const float* b2 = (const float*)d_in[5];
    const float* W3 = (const float*)d_in[6];
    const float* b3 = (const float*)d_in[7];
    float* out = (float*)d_out;

    const int n = in_sizes[1];                 // 131072 rows
    int* counter = (int*)d_ws;                 // [0]: work-queue counter
    int* offsets = (int*)d_ws + 64;            // (NGRAPHS+1) ints, 256B-aligned

    find_offsets_kernel<<<(n + 255) / 256, 256, 0, stream>>>(batch, n, offsets,
                                                             counter);
    pool_mlp_ws_kernel<<<POOL_BLOCKS, 384, 0, stream>>>(features, offsets,
                                                        W1, b1, W2, b2, W3, b3,
                                                        out, counter);
}